// Round 14
// baseline (107.754 us; speedup 1.0000x reference)
//
#include <hip/hip_runtime.h>
#include <hip/hip_bf16.h>

#define CAP 32          // per-node bucket capacity (Poisson(6): P(deg>32) ~ 1e-12)
#define OVF_MAX 4096

typedef _Float16 h2 __attribute__((ext_vector_type(2)));
typedef _Float16 h8 __attribute__((ext_vector_type(8)));
typedef __attribute__((ext_vector_type(8))) unsigned short ushort8v;
typedef __attribute__((ext_vector_type(4))) float f32x4;

__device__ __forceinline__ unsigned short f2h_bits(float f) {
    union { _Float16 h; unsigned short u; } v;
    v.h = (_Float16)f;
    return v.u;
}

// prep: blocks [0,64)       -> W1/W2 permute to MFMA-fragment-linear fp16
//       blocks [64,64+nxb)  -> x (f32) -> xh (fp16), 8 elems/thread
//       blocks [64+nxb,...) -> count + DIRECT bucket scatter, 4 edges/thread
//                              (independent chains -> 4 atomics in flight)
__global__ __launch_bounds__(256) void prep_kernel(
    const float* __restrict__ W1, const float* __restrict__ W2,
    const float* __restrict__ x,
    const int* __restrict__ src, const int* __restrict__ dst,
    const float* __restrict__ ew,
    unsigned short* __restrict__ wtf1, unsigned short* __restrict__ wtf2,
    unsigned short* __restrict__ xh, int* __restrict__ cnt,
    int2* __restrict__ esrt, int4* __restrict__ ovf, int* __restrict__ ovf_cnt,
    int n8, int E, int nxb)
{
    int bid = blockIdx.x;
    if (bid < 64) {
        int t = bid * 256 + threadIdx.x;   // 0..16383
        int k = t >> 7, j = t & 127;
        int jt = j >> 4, r = j & 15, kt = k >> 5, kg = (k >> 3) & 3, e = k & 7;
        int flin = (jt * 4 + kt) * 512 + (kg * 16 + r) * 8 + e;
        wtf1[flin] = f2h_bits(W1[t]);
        wtf2[flin] = f2h_bits(W2[t]);
        return;
    }
    if (bid < 64 + nxb) {
        int t = (bid - 64) * 256 + threadIdx.x;
        if (t >= n8) return;
        float4 x0 = reinterpret_cast<const float4*>(x)[(size_t)t * 2];
        float4 x1 = reinterpret_cast<const float4*>(x)[(size_t)t * 2 + 1];
        ushort8v o;
        o[0] = f2h_bits(x0.x); o[1] = f2h_bits(x0.y);
        o[2] = f2h_bits(x0.z); o[3] = f2h_bits(x0.w);
        o[4] = f2h_bits(x1.x); o[5] = f2h_bits(x1.y);
        o[6] = f2h_bits(x1.z); o[7] = f2h_bits(x1.w);
        reinterpret_cast<ushort8v*>(xh)[t] = o;
        return;
    }
    // edge phase: 4 edges per thread (coalesced strided), batched chains
    int e0 = (bid - 64 - nxb) * 1024 + threadIdx.x;
    int  d[4], s[4];
    float w[4];
    bool ok[4];
    #pragma unroll
    for (int j = 0; j < 4; ++j) {
        int e = e0 + j * 256;
        ok[j] = (e < E);
        d[j] = ok[j] ? dst[e] : 0;
        s[j] = ok[j] ? src[e] : 0;
        w[j] = ok[j] ? ew[e]  : 0.f;
    }
    int r[4];
    #pragma unroll
    for (int j = 0; j < 4; ++j)
        r[j] = ok[j] ? atomicAdd(&cnt[d[j]], 1) : 0;
    #pragma unroll
    for (int j = 0; j < 4; ++j) {
        if (!ok[j]) continue;
        _Float16 wh = (_Float16)w[j];
        union { h2 h; int i; } uw; uw.h = (h2){wh, wh};
        int2 rec = make_int2(s[j], uw.i);
        if (r[j] < CAP) {
            esrt[(size_t)d[j] * CAP + r[j]] = rec;
        } else {
            int o = atomicAdd(ovf_cnt, 1);
            if (o < OVF_MAX) ovf[o] = make_int4(d[j], rec.x, rec.y, 0);
        }
    }
}

// ---- Fused: bucket gather -> LDS -> 2x f16 MFMA. 128 thr / 32 nodes / 8KB LDS.
__global__ __launch_bounds__(128, 4) void fused_kernel(
    const unsigned short* __restrict__ xh, const int* __restrict__ cnt,
    const int2* __restrict__ esrt,
    const int4* __restrict__ ovf, const int* __restrict__ ovf_cnt,
    const unsigned short* __restrict__ wtf1,
    const unsigned short* __restrict__ wtf2,
    const float* __restrict__ b1, const float* __restrict__ b2,
    float* __restrict__ y, int N)
{
    __shared__ __align__(16) unsigned short Hs[32 * 128];
    int tid = threadIdx.x;
    int node0 = blockIdx.x * 32;
    int ovfc = *ovf_cnt;   // ~always 0; uniform L2-hit load

    // Phase 1: gather. 8 groups x 16 lanes; group g owns rows {g, 8+g, 16+g, 24+g}.
    {
        int g = tid >> 4, l = tid & 15;
        const h8* xr = reinterpret_cast<const h8*>(xh);

        int degA[4];
        #pragma unroll
        for (int it = 0; it < 4; ++it) {
            int node = node0 + it * 8 + g;
            int nn = (node < N) ? node : N - 1;
            degA[it] = cnt[nn];
        }
        int2 evA[4];
        h8 selfA[4];
        #pragma unroll
        for (int it = 0; it < 4; ++it) {
            int node = node0 + it * 8 + g;
            int nn = (node < N) ? node : N - 1;
            evA[it] = make_int2(0, 0);
            if (l < min(degA[it], CAP)) evA[it] = esrt[(size_t)nn * CAP + l];
            selfA[it] = xr[(size_t)nn * 16 + l];
        }

        #pragma unroll
        for (int it = 0; it < 4; ++it) {
            int m = it * 8 + g;
            int node = node0 + m;
            int nn = (node < N) ? node : N - 1;
            h8 acc = selfA[it];                    // self-term (EPS=0)
            int deg = min(degA[it], CAP);
            int2 ev = evA[it];
            for (int base = 0; base < deg; base += 16) {
                int cnt2 = min(deg - base, 16);
                for (int j = 0; j < cnt2; j += 8) {
                    h8 v[8]; int wb[8];
                    #pragma unroll
                    for (int q = 0; q < 8; ++q) {
                        int sq = __shfl(ev.x, j + q, 16);
                        wb[q]  = __shfl(ev.y, j + q, 16);
                        v[q] = xr[(size_t)sq * 16 + l];
                    }
                    #pragma unroll
                    for (int q = 0; q < 8; ++q) {
                        union { int4 i; h8 h; } uw;
                        uw.i = make_int4(wb[q], wb[q], wb[q], wb[q]);
                        acc += uw.h * v[q];        // 4x v_pk_fma_f16 (pads w=0)
                    }
                }
                // next 16-batch metadata (deg in (16,32])
                ev = make_int2(0, 0);
                if (base + 16 + l < deg) ev = esrt[(size_t)nn * CAP + base + 16 + l];
            }
            // exact overflow path (deg > CAP): scan tiny COO list
            if (ovfc > 0 && degA[it] > CAP && node < N) {
                for (int o = 0; o < ovfc && o < OVF_MAX; ++o) {
                    int4 t4 = ovf[o];
                    if (t4.x == node) {
                        union { int4 i; h8 h; } uw;
                        uw.i = make_int4(t4.z, t4.z, t4.z, t4.z);
                        acc += uw.h * xr[(size_t)t4.y * 16 + l];
                    }
                }
            }
            // lane l holds chunk l (8 elems); swizzled chunk slot l ^ (m&7)
            int soff = m * 128 + ((l ^ (m & 7)) << 3);
            *reinterpret_cast<h8*>(&Hs[soff]) = acc;
        }
    }
    __syncthreads();

    int wave = tid >> 6, lane = tid & 63;   // wave in {0,1}
    int r = lane & 15, kg = lane >> 4;
    int row0 = node0 + wave * 16;
    int mr = wave * 16 + r;

    h8 a[4];
    #pragma unroll
    for (int kt = 0; kt < 4; ++kt)
        a[kt] = *reinterpret_cast<const h8*>(
            &Hs[mr * 128 + (((kt * 4 + kg) ^ (r & 7)) << 3)]);

    f32x4 acc1[8];
    #pragma unroll
    for (int jt = 0; jt < 8; ++jt) acc1[jt] = {0.f, 0.f, 0.f, 0.f};

    #pragma unroll
    for (int jt = 0; jt < 8; ++jt) {
        #pragma unroll
        for (int kt = 0; kt < 4; ++kt) {
            h8 b = *reinterpret_cast<const h8*>(
                wtf1 + ((jt * 4 + kt) << 9) + (lane << 3));   // coalesced
            acc1[jt] = __builtin_amdgcn_mfma_f32_16x16x32_f16(a[kt], b, acc1[jt], 0, 0, 0);
        }
    }

    #pragma unroll
    for (int jt = 0; jt < 8; ++jt) {
        float bias = b1[jt * 16 + r];
        int col = jt * 16 + r;
        #pragma unroll
        for (int reg = 0; reg < 4; ++reg) {
            int m2 = wave * 16 + kg * 4 + reg;
            float h = fmaxf(acc1[jt][reg] + bias, 0.0f);
            Hs[m2 * 128 + (((col >> 3) ^ (m2 & 7)) << 3) + (col & 7)] = f2h_bits(h);
        }
    }
    __syncthreads();

    h8 a2[4];
    #pragma unroll
    for (int kt = 0; kt < 4; ++kt)
        a2[kt] = *reinterpret_cast<const h8*>(
            &Hs[mr * 128 + (((kt * 4 + kg) ^ (r & 7)) << 3)]);

    f32x4 acc2[8];
    #pragma unroll
    for (int jt = 0; jt < 8; ++jt) acc2[jt] = {0.f, 0.f, 0.f, 0.f};

    #pragma unroll
    for (int jt = 0; jt < 8; ++jt) {
        #pragma unroll
        for (int kt = 0; kt < 4; ++kt) {
            h8 b = *reinterpret_cast<const h8*>(
                wtf2 + ((jt * 4 + kt) << 9) + (lane << 3));
            acc2[jt] = __builtin_amdgcn_mfma_f32_16x16x32_f16(a2[kt], b, acc2[jt], 0, 0, 0);
        }
    }

    #pragma unroll
    for (int jt = 0; jt < 8; ++jt) {
        float bias = b2[jt * 16 + r];
        #pragma unroll
        for (int reg = 0; reg < 4; ++reg) {
            int orow = row0 + kg * 4 + reg;
            if (orow < N)
                y[(size_t)orow * 128 + jt * 16 + r] = acc2[jt][reg] + bias;
        }
    }
}

extern "C" void kernel_launch(void* const* d_in, const int* in_sizes, int n_in,
                              void* d_out, int out_size, void* d_ws, size_t ws_size,
                              hipStream_t stream) {
    const float* x  = (const float*)d_in[0];
    const int*   ei = (const int*)d_in[1];      // [2,E] as int32
    const float* ew = (const float*)d_in[2];
    const float* W1 = (const float*)d_in[3];
    const float* b1 = (const float*)d_in[4];
    const float* W2 = (const float*)d_in[5];
    const float* b2 = (const float*)d_in[6];
    float* y = (float*)d_out;

    int N = in_sizes[0] / 128;   // 100000
    int E = in_sizes[2];         // 600000
    const size_t ND = (size_t)N * 128;
    int n8 = (int)(ND / 8);
    int nxb = (n8 + 255) / 256;
    int nhist = (E + 1023) / 1024;   // 4 edges/thread

    char* ws = (char*)d_ws;
    size_t off = 0;
    auto bump = [&](size_t bytes) {
        void* p = ws + off;
        off += (bytes + 255) & ~(size_t)255;
        return p;
    };
    // zero-region first (one memset covers cnt + ovf_cnt)
    size_t zstart = off;
    int*            cnt     = (int*)bump((size_t)N * 4);
    int*            ovf_cnt = (int*)bump(256);
    size_t zbytes = off - zstart;
    unsigned short* wtf1    = (unsigned short*)bump(128 * 128 * 2);
    unsigned short* wtf2    = (unsigned short*)bump(128 * 128 * 2);
    unsigned short* xh      = (unsigned short*)bump(ND * 2);           // 25.6 MB
    int2*           esrt    = (int2*)bump((size_t)N * CAP * 8);        // 25.6 MB
    int4*           ovf     = (int4*)bump((size_t)OVF_MAX * 16);       // 64 KB

    const int* src = ei;
    const int* dst = ei + E;

    hipMemsetAsync(ws + zstart, 0, zbytes, stream);
    prep_kernel<<<64 + nxb + nhist, 256, 0, stream>>>(
        W1, W2, x, src, dst, ew, wtf1, wtf2, xh, cnt, esrt, ovf, ovf_cnt,
        n8, E, nxb);
    fused_kernel<<<(N + 31) / 32, 128, 0, stream>>>(
        xh, cnt, esrt, ovf, ovf_cnt, wtf1, wtf2, b1, b2, y, N);
}

// Round 15
// 103.623 us; speedup vs baseline: 1.0399x; 1.0399x over previous
//
#include <hip/hip_runtime.h>
#include <hip/hip_bf16.h>

#define CAP 16          // per-node bucket (Poisson(6): P(deg>16) ~ 2.4e-4 -> ovf COO)
#define OVF_MAX 8192

typedef _Float16 h2 __attribute__((ext_vector_type(2)));
typedef _Float16 h8 __attribute__((ext_vector_type(8)));
typedef __attribute__((ext_vector_type(8))) unsigned short ushort8v;
typedef __attribute__((ext_vector_type(4))) float f32x4;

__device__ __forceinline__ unsigned short f2h_bits(float f) {
    union { _Float16 h; unsigned short u; } v;
    v.h = (_Float16)f;
    return v.u;
}

// prep: blocks [0,64)       -> W1/W2 permute to MFMA-fragment-linear fp16
//       blocks [64,64+nxb)  -> x (f32) -> xh (fp16), 8 elems/thread
//       blocks [64+nxb,...) -> count + DIRECT bucket scatter (1 edge/thread)
__global__ __launch_bounds__(256) void prep_kernel(
    const float* __restrict__ W1, const float* __restrict__ W2,
    const float* __restrict__ x,
    const int* __restrict__ src, const int* __restrict__ dst,
    const float* __restrict__ ew,
    unsigned short* __restrict__ wtf1, unsigned short* __restrict__ wtf2,
    unsigned short* __restrict__ xh, int* __restrict__ cnt,
    int2* __restrict__ esrt, int4* __restrict__ ovf, int* __restrict__ ovf_cnt,
    int n8, int E, int nxb)
{
    int bid = blockIdx.x;
    if (bid < 64) {
        int t = bid * 256 + threadIdx.x;   // 0..16383
        int k = t >> 7, j = t & 127;
        int jt = j >> 4, r = j & 15, kt = k >> 5, kg = (k >> 3) & 3, e = k & 7;
        int flin = (jt * 4 + kt) * 512 + (kg * 16 + r) * 8 + e;
        wtf1[flin] = f2h_bits(W1[t]);
        wtf2[flin] = f2h_bits(W2[t]);
        return;
    }
    if (bid < 64 + nxb) {
        int t = (bid - 64) * 256 + threadIdx.x;
        if (t >= n8) return;
        float4 x0 = reinterpret_cast<const float4*>(x)[(size_t)t * 2];
        float4 x1 = reinterpret_cast<const float4*>(x)[(size_t)t * 2 + 1];
        ushort8v o;
        o[0] = f2h_bits(x0.x); o[1] = f2h_bits(x0.y);
        o[2] = f2h_bits(x0.z); o[3] = f2h_bits(x0.w);
        o[4] = f2h_bits(x1.x); o[5] = f2h_bits(x1.y);
        o[6] = f2h_bits(x1.z); o[7] = f2h_bits(x1.w);
        reinterpret_cast<ushort8v*>(xh)[t] = o;
        return;
    }
    int e = (bid - 64 - nxb) * 256 + threadIdx.x;
    if (e >= E) return;
    int d = dst[e];
    int r = atomicAdd(&cnt[d], 1);
    _Float16 wh = (_Float16)ew[e];
    union { h2 h; int i; } uw; uw.h = (h2){wh, wh};
    int2 rec = make_int2(src[e], uw.i);
    if (r < CAP) {
        esrt[(size_t)d * CAP + r] = rec;
    } else {
        int o = atomicAdd(ovf_cnt, 1);
        if (o < OVF_MAX) ovf[o] = make_int4(d, rec.x, rec.y, 0);
    }
}

// ---- Fused: bucket gather (single 16-batch) -> LDS -> 2x f16 MFMA ----
__global__ __launch_bounds__(128, 4) void fused_kernel(
    const unsigned short* __restrict__ xh, const int* __restrict__ cnt,
    const int2* __restrict__ esrt,
    const int4* __restrict__ ovf, const int* __restrict__ ovf_cnt,
    const unsigned short* __restrict__ wtf1,
    const unsigned short* __restrict__ wtf2,
    const float* __restrict__ b1, const float* __restrict__ b2,
    float* __restrict__ y, int N)
{
    __shared__ __align__(16) unsigned short Hs[32 * 128];
    int tid = threadIdx.x;
    int node0 = blockIdx.x * 32;
    int ovfc = *ovf_cnt;   // ~50 entries; uniform L2-hit load

    // Phase 1: gather. 8 groups x 16 lanes; group g owns rows {g, 8+g, 16+g, 24+g}.
    // CAP=16: exactly one bucket record per lane -> single batch, no reload.
    {
        int g = tid >> 4, l = tid & 15;
        const h8* xr = reinterpret_cast<const h8*>(xh);

        int degA[4];
        #pragma unroll
        for (int it = 0; it < 4; ++it) {
            int node = node0 + it * 8 + g;
            int nn = (node < N) ? node : N - 1;
            degA[it] = cnt[nn];
        }
        int2 evA[4];
        h8 selfA[4];
        #pragma unroll
        for (int it = 0; it < 4; ++it) {
            int node = node0 + it * 8 + g;
            int nn = (node < N) ? node : N - 1;
            evA[it] = make_int2(0, 0);
            if (l < min(degA[it], CAP)) evA[it] = esrt[(size_t)nn * CAP + l];
            selfA[it] = xr[(size_t)nn * 16 + l];
        }

        #pragma unroll
        for (int it = 0; it < 4; ++it) {
            int m = it * 8 + g;
            int node = node0 + m;
            h8 acc = selfA[it];                    // self-term (EPS=0)
            int deg = min(degA[it], CAP);
            int2 ev = evA[it];
            for (int j = 0; j < deg; j += 8) {
                h8 v[8]; int wb[8];
                #pragma unroll
                for (int q = 0; q < 8; ++q) {
                    int sq = __shfl(ev.x, j + q, 16);
                    wb[q]  = __shfl(ev.y, j + q, 16);
                    v[q] = xr[(size_t)sq * 16 + l];
                }
                #pragma unroll
                for (int q = 0; q < 8; ++q) {
                    union { int4 i; h8 h; } uw;
                    uw.i = make_int4(wb[q], wb[q], wb[q], wb[q]);
                    acc += uw.h * v[q];            // 4x v_pk_fma_f16 (pads w=0)
                }
            }
            // exact overflow path (deg > CAP): scan tiny COO list
            if (ovfc > 0 && degA[it] > CAP && node < N) {
                for (int o = 0; o < ovfc && o < OVF_MAX; ++o) {
                    int4 t4 = ovf[o];
                    if (t4.x == node) {
                        union { int4 i; h8 h; } uw;
                        uw.i = make_int4(t4.z, t4.z, t4.z, t4.z);
                        acc += uw.h * xr[(size_t)t4.y * 16 + l];
                    }
                }
            }
            // lane l holds chunk l (8 elems); swizzled chunk slot l ^ (m&7)
            int soff = m * 128 + ((l ^ (m & 7)) << 3);
            *reinterpret_cast<h8*>(&Hs[soff]) = acc;
        }
    }
    __syncthreads();

    int wave = tid >> 6, lane = tid & 63;   // wave in {0,1}
    int r = lane & 15, kg = lane >> 4;
    int row0 = node0 + wave * 16;
    int mr = wave * 16 + r;

    h8 a[4];
    #pragma unroll
    for (int kt = 0; kt < 4; ++kt)
        a[kt] = *reinterpret_cast<const h8*>(
            &Hs[mr * 128 + (((kt * 4 + kg) ^ (r & 7)) << 3)]);

    f32x4 acc1[8];
    #pragma unroll
    for (int jt = 0; jt < 8; ++jt) acc1[jt] = {0.f, 0.f, 0.f, 0.f};

    #pragma unroll
    for (int jt = 0; jt < 8; ++jt) {
        #pragma unroll
        for (int kt = 0; kt < 4; ++kt) {
            h8 b = *reinterpret_cast<const h8*>(
                wtf1 + ((jt * 4 + kt) << 9) + (lane << 3));   // coalesced
            acc1[jt] = __builtin_amdgcn_mfma_f32_16x16x32_f16(a[kt], b, acc1[jt], 0, 0, 0);
        }
    }

    #pragma unroll
    for (int jt = 0; jt < 8; ++jt) {
        float bias = b1[jt * 16 + r];
        int col = jt * 16 + r;
        #pragma unroll
        for (int reg = 0; reg < 4; ++reg) {
            int m2 = wave * 16 + kg * 4 + reg;
            float h = fmaxf(acc1[jt][reg] + bias, 0.0f);
            Hs[m2 * 128 + (((col >> 3) ^ (m2 & 7)) << 3) + (col & 7)] = f2h_bits(h);
        }
    }
    __syncthreads();

    h8 a2[4];
    #pragma unroll
    for (int kt = 0; kt < 4; ++kt)
        a2[kt] = *reinterpret_cast<const h8*>(
            &Hs[mr * 128 + (((kt * 4 + kg) ^ (r & 7)) << 3)]);

    f32x4 acc2[8];
    #pragma unroll
    for (int jt = 0; jt < 8; ++jt) acc2[jt] = {0.f, 0.f, 0.f, 0.f};

    #pragma unroll
    for (int jt = 0; jt < 8; ++jt) {
        #pragma unroll
        for (int kt = 0; kt < 4; ++kt) {
            h8 b = *reinterpret_cast<const h8*>(
                wtf2 + ((jt * 4 + kt) << 9) + (lane << 3));
            acc2[jt] = __builtin_amdgcn_mfma_f32_16x16x32_f16(a2[kt], b, acc2[jt], 0, 0, 0);
        }
    }

    #pragma unroll
    for (int jt = 0; jt < 8; ++jt) {
        float bias = b2[jt * 16 + r];
        #pragma unroll
        for (int reg = 0; reg < 4; ++reg) {
            int orow = row0 + kg * 4 + reg;
            if (orow < N)
                y[(size_t)orow * 128 + jt * 16 + r] = acc2[jt][reg] + bias;
        }
    }
}

extern "C" void kernel_launch(void* const* d_in, const int* in_sizes, int n_in,
                              void* d_out, int out_size, void* d_ws, size_t ws_size,
                              hipStream_t stream) {
    const float* x  = (const float*)d_in[0];
    const int*   ei = (const int*)d_in[1];      // [2,E] as int32
    const float* ew = (const float*)d_in[2];
    const float* W1 = (const float*)d_in[3];
    const float* b1 = (const float*)d_in[4];
    const float* W2 = (const float*)d_in[5];
    const float* b2 = (const float*)d_in[6];
    float* y = (float*)d_out;

    int N = in_sizes[0] / 128;   // 100000
    int E = in_sizes[2];         // 600000
    const size_t ND = (size_t)N * 128;
    int n8 = (int)(ND / 8);
    int nxb = (n8 + 255) / 256;
    int nhist = (E + 255) / 256;

    char* ws = (char*)d_ws;
    size_t off = 0;
    auto bump = [&](size_t bytes) {
        void* p = ws + off;
        off += (bytes + 255) & ~(size_t)255;
        return p;
    };
    // zero-region first (one memset covers cnt + ovf_cnt)
    size_t zstart = off;
    int*            cnt     = (int*)bump((size_t)N * 4);
    int*            ovf_cnt = (int*)bump(256);
    size_t zbytes = off - zstart;
    unsigned short* wtf1    = (unsigned short*)bump(128 * 128 * 2);
    unsigned short* wtf2    = (unsigned short*)bump(128 * 128 * 2);
    unsigned short* xh      = (unsigned short*)bump(ND * 2);           // 25.6 MB
    int2*           esrt    = (int2*)bump((size_t)N * CAP * 8);        // 12.8 MB
    int4*           ovf     = (int4*)bump((size_t)OVF_MAX * 16);       // 128 KB

    const int* src = ei;
    const int* dst = ei + E;

    hipMemsetAsync(ws + zstart, 0, zbytes, stream);
    prep_kernel<<<64 + nxb + nhist, 256, 0, stream>>>(
        W1, W2, x, src, dst, ew, wtf1, wtf2, xh, cnt, esrt, ovf, ovf_cnt,
        n8, E, nxb);
    fused_kernel<<<(N + 31) / 32, 128, 0, stream>>>(
        xh, cnt, esrt, ovf, ovf_cnt, wtf1, wtf2, b1, b2, y, N);
}

// Round 16
// 101.803 us; speedup vs baseline: 1.0585x; 1.0179x over previous
//
#include <hip/hip_runtime.h>
#include <hip/hip_bf16.h>

#define CAP 16          // per-node bucket (Poisson(6): P(deg>16) ~ 2.4e-4 -> ovf COO)
#define OVF_MAX 8192

typedef _Float16 h2 __attribute__((ext_vector_type(2)));
typedef _Float16 h8 __attribute__((ext_vector_type(8)));
typedef __attribute__((ext_vector_type(8))) unsigned short ushort8v;
typedef __attribute__((ext_vector_type(4))) float f32x4;

__device__ __forceinline__ unsigned short f2h_bits(float f) {
    union { _Float16 h; unsigned short u; } v;
    v.h = (_Float16)f;
    return v.u;
}

// Edge bucket build: 1 edge/thread. rec packs (src:17 | w:15 fixed-point).
__global__ __launch_bounds__(256) void edge_kernel(
    const int* __restrict__ src, const int* __restrict__ dst,
    const float* __restrict__ ew, int* __restrict__ cnt,
    unsigned int* __restrict__ esrt, int4* __restrict__ ovf,
    int* __restrict__ ovf_cnt, int E)
{
    int e = blockIdx.x * 256 + threadIdx.x;
    if (e >= E) return;
    int d = dst[e];
    int r = atomicAdd(&cnt[d], 1);
    int wq = (int)(ew[e] * 32767.f + 0.5f);
    unsigned int rec = ((unsigned int)src[e] << 15) | (unsigned int)wq;
    if (r < CAP) {
        esrt[(size_t)d * CAP + r] = rec;
    } else {
        int o = atomicAdd(ovf_cnt, 1);
        if (o < OVF_MAX) ovf[o] = make_int4(d, src[e], __float_as_int(ew[e]), 0);
    }
}

// W permute + x -> fp16 conversion (streaming).
__global__ __launch_bounds__(256) void convw_kernel(
    const float* __restrict__ W1, const float* __restrict__ W2,
    const float* __restrict__ x,
    unsigned short* __restrict__ wtf1, unsigned short* __restrict__ wtf2,
    unsigned short* __restrict__ xh, int n8)
{
    int bid = blockIdx.x;
    if (bid < 64) {
        int t = bid * 256 + threadIdx.x;   // 0..16383
        int k = t >> 7, j = t & 127;
        int jt = j >> 4, r = j & 15, kt = k >> 5, kg = (k >> 3) & 3, e = k & 7;
        int flin = (jt * 4 + kt) * 512 + (kg * 16 + r) * 8 + e;
        wtf1[flin] = f2h_bits(W1[t]);
        wtf2[flin] = f2h_bits(W2[t]);
        return;
    }
    int t = (bid - 64) * 256 + threadIdx.x;
    if (t >= n8) return;
    float4 x0 = reinterpret_cast<const float4*>(x)[(size_t)t * 2];
    float4 x1 = reinterpret_cast<const float4*>(x)[(size_t)t * 2 + 1];
    ushort8v o;
    o[0] = f2h_bits(x0.x); o[1] = f2h_bits(x0.y);
    o[2] = f2h_bits(x0.z); o[3] = f2h_bits(x0.w);
    o[4] = f2h_bits(x1.x); o[5] = f2h_bits(x1.y);
    o[6] = f2h_bits(x1.z); o[7] = f2h_bits(x1.w);
    reinterpret_cast<ushort8v*>(xh)[t] = o;
}

// ---- Fused: bucket gather (single 16-batch) -> LDS -> 2x f16 MFMA ----
__global__ __launch_bounds__(128, 4) void fused_kernel(
    const unsigned short* __restrict__ xh, const int* __restrict__ cnt,
    const unsigned int* __restrict__ esrt,
    const int4* __restrict__ ovf, const int* __restrict__ ovf_cnt,
    const unsigned short* __restrict__ wtf1,
    const unsigned short* __restrict__ wtf2,
    const float* __restrict__ b1, const float* __restrict__ b2,
    float* __restrict__ y, int N)
{
    __shared__ __align__(16) unsigned short Hs[32 * 128];
    int tid = threadIdx.x;
    int node0 = blockIdx.x * 32;
    int ovfc = *ovf_cnt;   // ~25 entries; uniform L2-hit load

    // Phase 1: gather. 8 groups x 16 lanes; group g owns rows {g, 8+g, 16+g, 24+g}.
    {
        int g = tid >> 4, l = tid & 15;
        const h8* xr = reinterpret_cast<const h8*>(xh);

        int degA[4];
        #pragma unroll
        for (int it = 0; it < 4; ++it) {
            int node = node0 + it * 8 + g;
            int nn = (node < N) ? node : N - 1;
            degA[it] = cnt[nn];
        }
        int sqA[4], wvA[4];          // per-lane decoded (src, packed-h2 weight)
        h8 selfA[4];
        #pragma unroll
        for (int it = 0; it < 4; ++it) {
            int node = node0 + it * 8 + g;
            int nn = (node < N) ? node : N - 1;
            unsigned int rec = 0;
            if (l < min(degA[it], CAP)) rec = esrt[(size_t)nn * CAP + l];
            sqA[it] = (int)(rec >> 15);
            _Float16 wh = (_Float16)((float)(rec & 32767u) * (1.f / 32767.f));
            union { h2 h; int i; } pw; pw.h = (h2){wh, wh};
            wvA[it] = pw.i;
            selfA[it] = xr[(size_t)nn * 16 + l];
        }

        #pragma unroll
        for (int it = 0; it < 4; ++it) {
            int m = it * 8 + g;
            int node = node0 + m;
            h8 acc = selfA[it];                    // self-term (EPS=0)
            int deg = min(degA[it], CAP);
            for (int j = 0; j < deg; j += 8) {
                h8 v[8]; int wb[8];
                #pragma unroll
                for (int q = 0; q < 8; ++q) {
                    int sq = __shfl(sqA[it], j + q, 16);
                    wb[q]  = __shfl(wvA[it], j + q, 16);
                    v[q] = xr[(size_t)sq * 16 + l];
                }
                #pragma unroll
                for (int q = 0; q < 8; ++q) {
                    union { int4 i; h8 h; } uw;
                    uw.i = make_int4(wb[q], wb[q], wb[q], wb[q]);
                    acc += uw.h * v[q];            // 4x v_pk_fma_f16 (pads w=0)
                }
            }
            // exact overflow path (deg > CAP): scan tiny COO list
            if (ovfc > 0 && degA[it] > CAP && node < N) {
                for (int o = 0; o < ovfc && o < OVF_MAX; ++o) {
                    int4 t4 = ovf[o];
                    if (t4.x == node) {
                        _Float16 wh = (_Float16)__int_as_float(t4.z);
                        union { h2 h; int i; } pw; pw.h = (h2){wh, wh};
                        union { int4 i; h8 h; } uw;
                        uw.i = make_int4(pw.i, pw.i, pw.i, pw.i);
                        acc += uw.h * xr[(size_t)t4.y * 16 + l];
                    }
                }
            }
            // lane l holds chunk l (8 elems); swizzled chunk slot l ^ (m&7)
            int soff = m * 128 + ((l ^ (m & 7)) << 3);
            *reinterpret_cast<h8*>(&Hs[soff]) = acc;
        }
    }
    __syncthreads();

    int wave = tid >> 6, lane = tid & 63;   // wave in {0,1}
    int r = lane & 15, kg = lane >> 4;
    int row0 = node0 + wave * 16;
    int mr = wave * 16 + r;

    h8 a[4];
    #pragma unroll
    for (int kt = 0; kt < 4; ++kt)
        a[kt] = *reinterpret_cast<const h8*>(
            &Hs[mr * 128 + (((kt * 4 + kg) ^ (r & 7)) << 3)]);

    f32x4 acc1[8];
    #pragma unroll
    for (int jt = 0; jt < 8; ++jt) acc1[jt] = {0.f, 0.f, 0.f, 0.f};

    #pragma unroll
    for (int jt = 0; jt < 8; ++jt) {
        #pragma unroll
        for (int kt = 0; kt < 4; ++kt) {
            h8 b = *reinterpret_cast<const h8*>(
                wtf1 + ((jt * 4 + kt) << 9) + (lane << 3));   // coalesced
            acc1[jt] = __builtin_amdgcn_mfma_f32_16x16x32_f16(a[kt], b, acc1[jt], 0, 0, 0);
        }
    }

    #pragma unroll
    for (int jt = 0; jt < 8; ++jt) {
        float bias = b1[jt * 16 + r];
        int col = jt * 16 + r;
        #pragma unroll
        for (int reg = 0; reg < 4; ++reg) {
            int m2 = wave * 16 + kg * 4 + reg;
            float h = fmaxf(acc1[jt][reg] + bias, 0.0f);
            Hs[m2 * 128 + (((col >> 3) ^ (m2 & 7)) << 3) + (col & 7)] = f2h_bits(h);
        }
    }
    __syncthreads();

    h8 a2[4];
    #pragma unroll
    for (int kt = 0; kt < 4; ++kt)
        a2[kt] = *reinterpret_cast<const h8*>(
            &Hs[mr * 128 + (((kt * 4 + kg) ^ (r & 7)) << 3)]);

    f32x4 acc2[8];
    #pragma unroll
    for (int jt = 0; jt < 8; ++jt) acc2[jt] = {0.f, 0.f, 0.f, 0.f};

    #pragma unroll
    for (int jt = 0; jt < 8; ++jt) {
        #pragma unroll
        for (int kt = 0; kt < 4; ++kt) {
            h8 b = *reinterpret_cast<const h8*>(
                wtf2 + ((jt * 4 + kt) << 9) + (lane << 3));
            acc2[jt] = __builtin_amdgcn_mfma_f32_16x16x32_f16(a2[kt], b, acc2[jt], 0, 0, 0);
        }
    }

    #pragma unroll
    for (int jt = 0; jt < 8; ++jt) {
        float bias = b2[jt * 16 + r];
        #pragma unroll
        for (int reg = 0; reg < 4; ++reg) {
            int orow = row0 + kg * 4 + reg;
            if (orow < N)
                y[(size_t)orow * 128 + jt * 16 + r] = acc2[jt][reg] + bias;
        }
    }
}

extern "C" void kernel_launch(void* const* d_in, const int* in_sizes, int n_in,
                              void* d_out, int out_size, void* d_ws, size_t ws_size,
                              hipStream_t stream) {
    const float* x  = (const float*)d_in[0];
    const int*   ei = (const int*)d_in[1];      // [2,E] as int32
    const float* ew = (const float*)d_in[2];
    const float* W1 = (const float*)d_in[3];
    const float* b1 = (const float*)d_in[4];
    const float* W2 = (const float*)d_in[5];
    const float* b2 = (const float*)d_in[6];
    float* y = (float*)d_out;

    int N = in_sizes[0] / 128;   // 100000
    int E = in_sizes[2];         // 600000
    const size_t ND = (size_t)N * 128;
    int n8 = (int)(ND / 8);
    int nxb = (n8 + 255) / 256;
    int nhist = (E + 255) / 256;

    char* ws = (char*)d_ws;
    size_t off = 0;
    auto bump = [&](size_t bytes) {
        void* p = ws + off;
        off += (bytes + 255) & ~(size_t)255;
        return p;
    };
    // zero-region first (one memset covers cnt + ovf_cnt)
    size_t zstart = off;
    int*            cnt     = (int*)bump((size_t)N * 4);
    int*            ovf_cnt = (int*)bump(256);
    size_t zbytes = off - zstart;
    unsigned short* wtf1    = (unsigned short*)bump(128 * 128 * 2);
    unsigned short* wtf2    = (unsigned short*)bump(128 * 128 * 2);
    unsigned short* xh      = (unsigned short*)bump(ND * 2);           // 25.6 MB
    unsigned int*   esrt    = (unsigned int*)bump((size_t)N * CAP * 4); // 6.4 MB
    int4*           ovf     = (int4*)bump((size_t)OVF_MAX * 16);       // 128 KB

    const int* src = ei;
    const int* dst = ei + E;

    hipMemsetAsync(ws + zstart, 0, zbytes, stream);
    edge_kernel<<<nhist, 256, 0, stream>>>(src, dst, ew, cnt, esrt, ovf,
                                           ovf_cnt, E);
    convw_kernel<<<64 + nxb, 256, 0, stream>>>(W1, W2, x, wtf1, wtf2, xh, n8);
    fused_kernel<<<(N + 31) / 32, 128, 0, stream>>>(
        xh, cnt, esrt, ovf, ovf_cnt, wtf1, wtf2, b1, b2, y, N);
}

// Round 17
// 99.468 us; speedup vs baseline: 1.0833x; 1.0235x over previous
//
#include <hip/hip_runtime.h>
#include <hip/hip_bf16.h>

#define CAP 16          // per-node bucket (Poisson(6): P(deg>16) ~ 2.4e-4 -> ovf COO)
#define OVF_MAX 8192

typedef _Float16 h2 __attribute__((ext_vector_type(2)));
typedef _Float16 h8 __attribute__((ext_vector_type(8)));
typedef __attribute__((ext_vector_type(8))) unsigned short ushort8v;
typedef __attribute__((ext_vector_type(4))) float f32x4;

__device__ __forceinline__ unsigned short f2h_bits(float f) {
    union { _Float16 h; unsigned short u; } v;
    v.h = (_Float16)f;
    return v.u;
}

// Edge bucket build: 1 edge/thread. rec packs (src:17 | w:15 fixed-point).
__global__ __launch_bounds__(256) void edge_kernel(
    const int* __restrict__ src, const int* __restrict__ dst,
    const float* __restrict__ ew, int* __restrict__ cnt,
    unsigned int* __restrict__ esrt, int4* __restrict__ ovf,
    int* __restrict__ ovf_cnt, int E)
{
    int e = blockIdx.x * 256 + threadIdx.x;
    if (e >= E) return;
    int d = dst[e];
    int r = atomicAdd(&cnt[d], 1);
    int wq = (int)(ew[e] * 32767.f + 0.5f);
    unsigned int rec = ((unsigned int)src[e] << 15) | (unsigned int)wq;
    if (r < CAP) {
        esrt[(size_t)d * CAP + r] = rec;
    } else {
        int o = atomicAdd(ovf_cnt, 1);
        if (o < OVF_MAX) ovf[o] = make_int4(d, src[e], __float_as_int(ew[e]), 0);
    }
}

// W permute + x -> fp16 conversion (streaming).
__global__ __launch_bounds__(256) void convw_kernel(
    const float* __restrict__ W1, const float* __restrict__ W2,
    const float* __restrict__ x,
    unsigned short* __restrict__ wtf1, unsigned short* __restrict__ wtf2,
    unsigned short* __restrict__ xh, int n8)
{
    int bid = blockIdx.x;
    if (bid < 64) {
        int t = bid * 256 + threadIdx.x;   // 0..16383
        int k = t >> 7, j = t & 127;
        int jt = j >> 4, r = j & 15, kt = k >> 5, kg = (k >> 3) & 3, e = k & 7;
        int flin = (jt * 4 + kt) * 512 + (kg * 16 + r) * 8 + e;
        wtf1[flin] = f2h_bits(W1[t]);
        wtf2[flin] = f2h_bits(W2[t]);
        return;
    }
    int t = (bid - 64) * 256 + threadIdx.x;
    if (t >= n8) return;
    float4 x0 = reinterpret_cast<const float4*>(x)[(size_t)t * 2];
    float4 x1 = reinterpret_cast<const float4*>(x)[(size_t)t * 2 + 1];
    ushort8v o;
    o[0] = f2h_bits(x0.x); o[1] = f2h_bits(x0.y);
    o[2] = f2h_bits(x0.z); o[3] = f2h_bits(x0.w);
    o[4] = f2h_bits(x1.x); o[5] = f2h_bits(x1.y);
    o[6] = f2h_bits(x1.z); o[7] = f2h_bits(x1.w);
    reinterpret_cast<ushort8v*>(xh)[t] = o;
}

// ---- Fused: bucket gather -> LDS -> 2x f16 MFMA -> coalesced f32 y ----
__global__ __launch_bounds__(128, 4) void fused_kernel(
    const unsigned short* __restrict__ xh, const int* __restrict__ cnt,
    const unsigned int* __restrict__ esrt,
    const int4* __restrict__ ovf, const int* __restrict__ ovf_cnt,
    const unsigned short* __restrict__ wtf1,
    const unsigned short* __restrict__ wtf2,
    const float* __restrict__ b1, const float* __restrict__ b2,
    float* __restrict__ y, int N)
{
    __shared__ __align__(16) unsigned short Hs[32 * 128];
    int tid = threadIdx.x;
    int node0 = blockIdx.x * 32;
    int ovfc = *ovf_cnt;   // ~25 entries; uniform L2-hit load

    // Phase 1: gather. 8 groups x 16 lanes; group g owns rows {g, 8+g, 16+g, 24+g}.
    {
        int g = tid >> 4, l = tid & 15;
        const h8* xr = reinterpret_cast<const h8*>(xh);

        int degA[4];
        #pragma unroll
        for (int it = 0; it < 4; ++it) {
            int node = node0 + it * 8 + g;
            int nn = (node < N) ? node : N - 1;
            degA[it] = cnt[nn];
        }
        int sqA[4], wvA[4];          // per-lane decoded (src, packed-h2 weight)
        h8 selfA[4];
        #pragma unroll
        for (int it = 0; it < 4; ++it) {
            int node = node0 + it * 8 + g;
            int nn = (node < N) ? node : N - 1;
            unsigned int rec = 0;
            if (l < min(degA[it], CAP)) rec = esrt[(size_t)nn * CAP + l];
            sqA[it] = (int)(rec >> 15);
            _Float16 wh = (_Float16)((float)(rec & 32767u) * (1.f / 32767.f));
            union { h2 h; int i; } pw; pw.h = (h2){wh, wh};
            wvA[it] = pw.i;
            selfA[it] = xr[(size_t)nn * 16 + l];
        }

        #pragma unroll
        for (int it = 0; it < 4; ++it) {
            int m = it * 8 + g;
            int node = node0 + m;
            h8 acc = selfA[it];                    // self-term (EPS=0)
            int deg = min(degA[it], CAP);
            for (int j = 0; j < deg; j += 8) {
                h8 v[8]; int wb[8];
                #pragma unroll
                for (int q = 0; q < 8; ++q) {
                    int sq = __shfl(sqA[it], j + q, 16);
                    wb[q]  = __shfl(wvA[it], j + q, 16);
                    v[q] = xr[(size_t)sq * 16 + l];
                }
                #pragma unroll
                for (int q = 0; q < 8; ++q) {
                    union { int4 i; h8 h; } uw;
                    uw.i = make_int4(wb[q], wb[q], wb[q], wb[q]);
                    acc += uw.h * v[q];            // 4x v_pk_fma_f16 (pads w=0)
                }
            }
            // exact overflow path (deg > CAP): scan tiny COO list
            if (ovfc > 0 && degA[it] > CAP && node < N) {
                for (int o = 0; o < ovfc && o < OVF_MAX; ++o) {
                    int4 t4 = ovf[o];
                    if (t4.x == node) {
                        _Float16 wh = (_Float16)__int_as_float(t4.z);
                        union { h2 h; int i; } pw; pw.h = (h2){wh, wh};
                        union { int4 i; h8 h; } uw;
                        uw.i = make_int4(pw.i, pw.i, pw.i, pw.i);
                        acc += uw.h * xr[(size_t)t4.y * 16 + l];
                    }
                }
            }
            // lane l holds chunk l (8 elems); swizzled chunk slot l ^ (m&7)
            int soff = m * 128 + ((l ^ (m & 7)) << 3);
            *reinterpret_cast<h8*>(&Hs[soff]) = acc;
        }
    }
    __syncthreads();

    int wave = tid >> 6, lane = tid & 63;   // wave in {0,1}
    int r = lane & 15, kg = lane >> 4;
    int mr = wave * 16 + r;

    h8 a[4];
    #pragma unroll
    for (int kt = 0; kt < 4; ++kt)
        a[kt] = *reinterpret_cast<const h8*>(
            &Hs[mr * 128 + (((kt * 4 + kg) ^ (r & 7)) << 3)]);

    f32x4 acc1[8];
    #pragma unroll
    for (int jt = 0; jt < 8; ++jt) acc1[jt] = {0.f, 0.f, 0.f, 0.f};

    #pragma unroll
    for (int jt = 0; jt < 8; ++jt) {
        #pragma unroll
        for (int kt = 0; kt < 4; ++kt) {
            h8 b = *reinterpret_cast<const h8*>(
                wtf1 + ((jt * 4 + kt) << 9) + (lane << 3));   // coalesced
            acc1[jt] = __builtin_amdgcn_mfma_f32_16x16x32_f16(a[kt], b, acc1[jt], 0, 0, 0);
        }
    }

    #pragma unroll
    for (int jt = 0; jt < 8; ++jt) {
        float bias = b1[jt * 16 + r];
        int col = jt * 16 + r;
        #pragma unroll
        for (int reg = 0; reg < 4; ++reg) {
            int m2 = wave * 16 + kg * 4 + reg;
            float h = fmaxf(acc1[jt][reg] + bias, 0.0f);
            Hs[m2 * 128 + (((col >> 3) ^ (m2 & 7)) << 3) + (col & 7)] = f2h_bits(h);
        }
    }
    __syncthreads();

    h8 a2[4];
    #pragma unroll
    for (int kt = 0; kt < 4; ++kt)
        a2[kt] = *reinterpret_cast<const h8*>(
            &Hs[mr * 128 + (((kt * 4 + kg) ^ (r & 7)) << 3)]);

    f32x4 acc2[8];
    #pragma unroll
    for (int jt = 0; jt < 8; ++jt) acc2[jt] = {0.f, 0.f, 0.f, 0.f};

    #pragma unroll
    for (int jt = 0; jt < 8; ++jt) {
        #pragma unroll
        for (int kt = 0; kt < 4; ++kt) {
            h8 b = *reinterpret_cast<const h8*>(
                wtf2 + ((jt * 4 + kt) << 9) + (lane << 3));
            acc2[jt] = __builtin_amdgcn_mfma_f32_16x16x32_f16(a2[kt], b, acc2[jt], 0, 0, 0);
        }
    }

    // Coalesced y epilogue: stage each wave's 16x128 f32 tile in LDS (8 KB,
    // reusing Hs), then store float4/lane (full 64B lines -> no RFO fetch).
    float* Hf = reinterpret_cast<float*>(Hs);
    #pragma unroll
    for (int p = 0; p < 2; ++p) {
        __syncthreads();
        if (wave == p) {
            #pragma unroll
            for (int jt = 0; jt < 8; ++jt) {
                float bias = b2[jt * 16 + r];
                #pragma unroll
                for (int reg = 0; reg < 4; ++reg)
                    Hf[(kg * 4 + reg) * 128 + jt * 16 + r] = acc2[jt][reg] + bias;
            }
        }
        __syncthreads();
        #pragma unroll
        for (int q = 0; q < 4; ++q) {
            int f = q * 128 + tid;         // float4 index in [0,512)
            int row = f >> 5, c4 = f & 31;
            int orow = node0 + p * 16 + row;
            if (orow < N)
                reinterpret_cast<float4*>(y)[(size_t)orow * 32 + c4] =
                    reinterpret_cast<const float4*>(Hf)[f];
        }
    }
}

extern "C" void kernel_launch(void* const* d_in, const int* in_sizes, int n_in,
                              void* d_out, int out_size, void* d_ws, size_t ws_size,
                              hipStream_t stream) {
    const float* x  = (const float*)d_in[0];
    const int*   ei = (const int*)d_in[1];      // [2,E] as int32
    const float* ew = (const float*)d_in[2];
    const float* W1 = (const float*)d_in[3];
    const float* b1 = (const float*)d_in[4];
    const float* W2 = (const float*)d_in[5];
    const float* b2 = (const float*)d_in[6];
    float* y = (float*)d_out;

    int N = in_sizes[0] / 128;   // 100000
    int E = in_sizes[2];         // 600000
    const size_t ND = (size_t)N * 128;
    int n8 = (int)(ND / 8);
    int nxb = (n8 + 255) / 256;
    int nhist = (E + 255) / 256;

    char* ws = (char*)d_ws;
    size_t off = 0;
    auto bump = [&](size_t bytes) {
        void* p = ws + off;
        off += (bytes + 255) & ~(size_t)255;
        return p;
    };
    // zero-region first (one memset covers cnt + ovf_cnt)
    size_t zstart = off;
    int*            cnt     = (int*)bump((size_t)N * 4);
    int*            ovf_cnt = (int*)bump(256);
    size_t zbytes = off - zstart;
    unsigned short* wtf1    = (unsigned short*)bump(128 * 128 * 2);
    unsigned short* wtf2    = (unsigned short*)bump(128 * 128 * 2);
    unsigned short* xh      = (unsigned short*)bump(ND * 2);           // 25.6 MB
    unsigned int*   esrt    = (unsigned int*)bump((size_t)N * CAP * 4); // 6.4 MB
    int4*           ovf     = (int4*)bump((size_t)OVF_MAX * 16);       // 128 KB

    const int* src = ei;
    const int* dst = ei + E;

    hipMemsetAsync(ws + zstart, 0, zbytes, stream);
    edge_kernel<<<nhist, 256, 0, stream>>>(src, dst, ew, cnt, esrt, ovf,
                                           ovf_cnt, E);
    convw_kernel<<<64 + nxb, 256, 0, stream>>>(W1, W2, x, wtf1, wtf2, xh, n8);
    fused_kernel<<<(N + 31) / 32, 128, 0, stream>>>(
        xh, cnt, esrt, ovf, ovf_cnt, wtf1, wtf2, b1, b2, y, N);
}

// Round 18
// 98.514 us; speedup vs baseline: 1.0938x; 1.0097x over previous
//
#include <hip/hip_runtime.h>
#include <hip/hip_bf16.h>

#define CAP 16          // per-node bucket (Poisson(6): P(deg>16) ~ 2.4e-4 -> ovf COO)
#define OVF_MAX 8192

typedef _Float16 h2 __attribute__((ext_vector_type(2)));
typedef _Float16 h8 __attribute__((ext_vector_type(8)));
typedef __attribute__((ext_vector_type(8))) unsigned short ushort8v;
typedef __attribute__((ext_vector_type(4))) float f32x4;

__device__ __forceinline__ unsigned short f2h_bits(float f) {
    union { _Float16 h; unsigned short u; } v;
    v.h = (_Float16)f;
    return v.u;
}

// Merged prologue (after cnt/ovf_cnt memset):
//   blocks [0, nhist)            -> edge bucket build (latency/atomic-bound)
//   blocks [nhist, nhist+64)     -> W1/W2 permute to fragment-linear fp16
//   blocks [nhist+64, ...)       -> x (f32) -> xh (fp16)  (BW-bound)
// Independent phases co-run on the CUs: latency work hides under streaming BW.
__global__ __launch_bounds__(256) void prep2_kernel(
    const int* __restrict__ src, const int* __restrict__ dst,
    const float* __restrict__ ew,
    const float* __restrict__ W1, const float* __restrict__ W2,
    const float* __restrict__ x,
    int* __restrict__ cnt, unsigned int* __restrict__ esrt,
    int4* __restrict__ ovf, int* __restrict__ ovf_cnt,
    unsigned short* __restrict__ wtf1, unsigned short* __restrict__ wtf2,
    unsigned short* __restrict__ xh,
    int E, int n8, int nhist)
{
    int bid = blockIdx.x;
    if (bid < nhist) {
        int e = bid * 256 + threadIdx.x;
        if (e >= E) return;
        int d = dst[e];
        int r = atomicAdd(&cnt[d], 1);
        int wq = (int)(ew[e] * 32767.f + 0.5f);
        unsigned int rec = ((unsigned int)src[e] << 15) | (unsigned int)wq;
        if (r < CAP) {
            esrt[(size_t)d * CAP + r] = rec;
        } else {
            int o = atomicAdd(ovf_cnt, 1);
            if (o < OVF_MAX) ovf[o] = make_int4(d, src[e], __float_as_int(ew[e]), 0);
        }
        return;
    }
    if (bid < nhist + 64) {
        int t = (bid - nhist) * 256 + threadIdx.x;   // 0..16383
        int k = t >> 7, j = t & 127;
        int jt = j >> 4, r = j & 15, kt = k >> 5, kg = (k >> 3) & 3, e = k & 7;
        int flin = (jt * 4 + kt) * 512 + (kg * 16 + r) * 8 + e;
        wtf1[flin] = f2h_bits(W1[t]);
        wtf2[flin] = f2h_bits(W2[t]);
        return;
    }
    int t = (bid - nhist - 64) * 256 + threadIdx.x;
    if (t >= n8) return;
    float4 x0 = reinterpret_cast<const float4*>(x)[(size_t)t * 2];
    float4 x1 = reinterpret_cast<const float4*>(x)[(size_t)t * 2 + 1];
    ushort8v o;
    o[0] = f2h_bits(x0.x); o[1] = f2h_bits(x0.y);
    o[2] = f2h_bits(x0.z); o[3] = f2h_bits(x0.w);
    o[4] = f2h_bits(x1.x); o[5] = f2h_bits(x1.y);
    o[6] = f2h_bits(x1.z); o[7] = f2h_bits(x1.w);
    reinterpret_cast<ushort8v*>(xh)[t] = o;
}

// ---- Fused: bucket gather -> LDS -> 2x f16 MFMA -> coalesced f32 y ----
__global__ __launch_bounds__(128, 4) void fused_kernel(
    const unsigned short* __restrict__ xh, const int* __restrict__ cnt,
    const unsigned int* __restrict__ esrt,
    const int4* __restrict__ ovf, const int* __restrict__ ovf_cnt,
    const unsigned short* __restrict__ wtf1,
    const unsigned short* __restrict__ wtf2,
    const float* __restrict__ b1, const float* __restrict__ b2,
    float* __restrict__ y, int N)
{
    __shared__ __align__(16) unsigned short Hs[32 * 128];
    int tid = threadIdx.x;
    int node0 = blockIdx.x * 32;
    int ovfc = *ovf_cnt;   // ~25 entries; uniform L2-hit load

    // Phase 1: gather. 8 groups x 16 lanes; group g owns rows {g, 8+g, 16+g, 24+g}.
    {
        int g = tid >> 4, l = tid & 15;
        const h8* xr = reinterpret_cast<const h8*>(xh);

        int degA[4];
        #pragma unroll
        for (int it = 0; it < 4; ++it) {
            int node = node0 + it * 8 + g;
            int nn = (node < N) ? node : N - 1;
            degA[it] = cnt[nn];
        }
        int sqA[4], wvA[4];          // per-lane decoded (src, packed-h2 weight)
        h8 selfA[4];
        #pragma unroll
        for (int it = 0; it < 4; ++it) {
            int node = node0 + it * 8 + g;
            int nn = (node < N) ? node : N - 1;
            unsigned int rec = 0;
            if (l < min(degA[it], CAP)) rec = esrt[(size_t)nn * CAP + l];
            sqA[it] = (int)(rec >> 15);
            _Float16 wh = (_Float16)((float)(rec & 32767u) * (1.f / 32767.f));
            union { h2 h; int i; } pw; pw.h = (h2){wh, wh};
            wvA[it] = pw.i;
            selfA[it] = xr[(size_t)nn * 16 + l];
        }

        #pragma unroll
        for (int it = 0; it < 4; ++it) {
            int m = it * 8 + g;
            int node = node0 + m;
            h8 acc = selfA[it];                    // self-term (EPS=0)
            int deg = min(degA[it], CAP);
            for (int j = 0; j < deg; j += 8) {
                h8 v[8]; int wb[8];
                #pragma unroll
                for (int q = 0; q < 8; ++q) {
                    int sq = __shfl(sqA[it], j + q, 16);
                    wb[q]  = __shfl(wvA[it], j + q, 16);
                    v[q] = xr[(size_t)sq * 16 + l];
                }
                #pragma unroll
                for (int q = 0; q < 8; ++q) {
                    union { int4 i; h8 h; } uw;
                    uw.i = make_int4(wb[q], wb[q], wb[q], wb[q]);
                    acc += uw.h * v[q];            // 4x v_pk_fma_f16 (pads w=0)
                }
            }
            // exact overflow path (deg > CAP): scan tiny COO list
            if (ovfc > 0 && degA[it] > CAP && node < N) {
                for (int o = 0; o < ovfc && o < OVF_MAX; ++o) {
                    int4 t4 = ovf[o];
                    if (t4.x == node) {
                        _Float16 wh = (_Float16)__int_as_float(t4.z);
                        union { h2 h; int i; } pw; pw.h = (h2){wh, wh};
                        union { int4 i; h8 h; } uw;
                        uw.i = make_int4(pw.i, pw.i, pw.i, pw.i);
                        acc += uw.h * xr[(size_t)t4.y * 16 + l];
                    }
                }
            }
            // lane l holds chunk l (8 elems); swizzled chunk slot l ^ (m&7)
            int soff = m * 128 + ((l ^ (m & 7)) << 3);
            *reinterpret_cast<h8*>(&Hs[soff]) = acc;
        }
    }
    __syncthreads();

    int wave = tid >> 6, lane = tid & 63;   // wave in {0,1}
    int r = lane & 15, kg = lane >> 4;
    int mr = wave * 16 + r;

    h8 a[4];
    #pragma unroll
    for (int kt = 0; kt < 4; ++kt)
        a[kt] = *reinterpret_cast<const h8*>(
            &Hs[mr * 128 + (((kt * 4 + kg) ^ (r & 7)) << 3)]);

    f32x4 acc1[8];
    #pragma unroll
    for (int jt = 0; jt < 8; ++jt) acc1[jt] = {0.f, 0.f, 0.f, 0.f};

    #pragma unroll
    for (int jt = 0; jt < 8; ++jt) {
        #pragma unroll
        for (int kt = 0; kt < 4; ++kt) {
            h8 b = *reinterpret_cast<const h8*>(
                wtf1 + ((jt * 4 + kt) << 9) + (lane << 3));   // coalesced
            acc1[jt] = __builtin_amdgcn_mfma_f32_16x16x32_f16(a[kt], b, acc1[jt], 0, 0, 0);
        }
    }

    #pragma unroll
    for (int jt = 0; jt < 8; ++jt) {
        float bias = b1[jt * 16 + r];
        int col = jt * 16 + r;
        #pragma unroll
        for (int reg = 0; reg < 4; ++reg) {
            int m2 = wave * 16 + kg * 4 + reg;
            float h = fmaxf(acc1[jt][reg] + bias, 0.0f);
            Hs[m2 * 128 + (((col >> 3) ^ (m2 & 7)) << 3) + (col & 7)] = f2h_bits(h);
        }
    }
    __syncthreads();

    h8 a2[4];
    #pragma unroll
    for (int kt = 0; kt < 4; ++kt)
        a2[kt] = *reinterpret_cast<const h8*>(
            &Hs[mr * 128 + (((kt * 4 + kg) ^ (r & 7)) << 3)]);

    f32x4 acc2[8];
    #pragma unroll
    for (int jt = 0; jt < 8; ++jt) acc2[jt] = {0.f, 0.f, 0.f, 0.f};

    #pragma unroll
    for (int jt = 0; jt < 8; ++jt) {
        #pragma unroll
        for (int kt = 0; kt < 4; ++kt) {
            h8 b = *reinterpret_cast<const h8*>(
                wtf2 + ((jt * 4 + kt) << 9) + (lane << 3));
            acc2[jt] = __builtin_amdgcn_mfma_f32_16x16x32_f16(a2[kt], b, acc2[jt], 0, 0, 0);
        }
    }

    // Coalesced y epilogue: stage each wave's 16x128 f32 tile in LDS (8 KB,
    // reusing Hs), then store float4/lane (full 64B lines -> no RFO fetch).
    float* Hf = reinterpret_cast<float*>(Hs);
    #pragma unroll
    for (int p = 0; p < 2; ++p) {
        __syncthreads();
        if (wave == p) {
            #pragma unroll
            for (int jt = 0; jt < 8; ++jt) {
                float bias = b2[jt * 16 + r];
                #pragma unroll
                for (int reg = 0; reg < 4; ++reg)
                    Hf[(kg * 4 + reg) * 128 + jt * 16 + r] = acc2[jt][reg] + bias;
            }
        }
        __syncthreads();
        #pragma unroll
        for (int q = 0; q < 4; ++q) {
            int f = q * 128 + tid;         // float4 index in [0,512)
            int row = f >> 5, c4 = f & 31;
            int orow = node0 + p * 16 + row;
            if (orow < N)
                reinterpret_cast<float4*>(y)[(size_t)orow * 32 + c4] =
                    reinterpret_cast<const float4*>(Hf)[f];
        }
    }
}

extern "C" void kernel_launch(void* const* d_in, const int* in_sizes, int n_in,
                              void* d_out, int out_size, void* d_ws, size_t ws_size,
                              hipStream_t stream) {
    const float* x  = (const float*)d_in[0];
    const int*   ei = (const int*)d_in[1];      // [2,E] as int32
    const float* ew = (const float*)d_in[2];
    const float* W1 = (const float*)d_in[3];
    const float* b1 = (const float*)d_in[4];
    const float* W2 = (const float*)d_in[5];
    const float* b2 = (const float*)d_in[6];
    float* y = (float*)d_out;

    int N = in_sizes[0] / 128;   // 100000
    int E = in_sizes[2];         // 600000
    const size_t ND = (size_t)N * 128;
    int n8 = (int)(ND / 8);
    int nxb = (n8 + 255) / 256;
    int nhist = (E + 255) / 256;

    char* ws = (char*)d_ws;
    size_t off = 0;
    auto bump = [&](size_t bytes) {
        void* p = ws + off;
        off += (bytes + 255) & ~(size_t)255;
        return p;
    };
    // zero-region first (one memset covers cnt + ovf_cnt)
    size_t zstart = off;
    int*            cnt     = (int*)bump((size_t)N * 4);
    int*            ovf_cnt = (int*)bump(256);
    size_t zbytes = off - zstart;
    unsigned short* wtf1    = (unsigned short*)bump(128 * 128 * 2);
    unsigned short* wtf2    = (unsigned short*)bump(128 * 128 * 2);
    unsigned short* xh      = (unsigned short*)bump(ND * 2);           // 25.6 MB
    unsigned int*   esrt    = (unsigned int*)bump((size_t)N * CAP * 4); // 6.4 MB
    int4*           ovf     = (int4*)bump((size_t)OVF_MAX * 16);       // 128 KB

    const int* src = ei;
    const int* dst = ei + E;

    hipMemsetAsync(ws + zstart, 0, zbytes, stream);
    prep2_kernel<<<nhist + 64 + nxb, 256, 0, stream>>>(
        src, dst, ew, W1, W2, x, cnt, esrt, ovf, ovf_cnt,
        wtf1, wtf2, xh, E, n8, nhist);
    fused_kernel<<<(N + 31) / 32, 128, 0, stream>>>(
        xh, cnt, esrt, ovf, ovf_cnt, wtf1, wtf2, b1, b2, y, N);
}

// Round 19
// 90.761 us; speedup vs baseline: 1.1872x; 1.0854x over previous
//
#include <hip/hip_runtime.h>
#include <hip/hip_bf16.h>

#define CAP 16          // per-node bucket (Poisson(6): P(deg>16) ~ 2.4e-4 -> ovf COO)
#define OVF_MAX 8192

typedef _Float16 h2 __attribute__((ext_vector_type(2)));
typedef _Float16 h8 __attribute__((ext_vector_type(8)));
typedef __attribute__((ext_vector_type(8))) unsigned short ushort8v;
typedef __attribute__((ext_vector_type(4))) float f32x4;

__device__ __forceinline__ unsigned short f2h_bits(float f) {
    union { _Float16 h; unsigned short u; } v;
    v.h = (_Float16)f;
    return v.u;
}

// Merged prologue with Bresenham role interleave: edge blocks (latency-bound)
// are striped uniformly among conversion blocks (BW-bound) so both kinds are
// resident simultaneously — overlap instead of phase-drain (R18 lesson:
// 2344 edge blocks alone oversubscribe the 8192-wave chip, so contiguous
// role ranges serialize).
__global__ __launch_bounds__(256) void prep2_kernel(
    const int* __restrict__ src, const int* __restrict__ dst,
    const float* __restrict__ ew,
    const float* __restrict__ W1, const float* __restrict__ W2,
    const float* __restrict__ x,
    int* __restrict__ cnt, unsigned int* __restrict__ esrt,
    int4* __restrict__ ovf, int* __restrict__ ovf_cnt,
    unsigned short* __restrict__ wtf1, unsigned short* __restrict__ wtf2,
    unsigned short* __restrict__ xh,
    int E, int n8, int nedge, int ntot)
{
    int bid = blockIdx.x;
    int eprev = (int)(((long long)bid * nedge) / ntot);
    int enext = (int)(((long long)(bid + 1) * nedge) / ntot);
    if (enext > eprev) {
        // ---- edge block #eprev: bucket build ----
        int e = eprev * 256 + threadIdx.x;
        if (e >= E) return;
        int d = dst[e];
        int r = atomicAdd(&cnt[d], 1);
        int wq = (int)(ew[e] * 32767.f + 0.5f);
        unsigned int rec = ((unsigned int)src[e] << 15) | (unsigned int)wq;
        if (r < CAP) {
            esrt[(size_t)d * CAP + r] = rec;
        } else {
            int o = atomicAdd(ovf_cnt, 1);
            if (o < OVF_MAX) ovf[o] = make_int4(d, src[e], __float_as_int(ew[e]), 0);
        }
        return;
    }
    int cb = bid - enext;   // conversion-block index (edge blocks before bid = enext)
    if (cb < 64) {
        // ---- W1/W2 permute to MFMA-fragment-linear fp16 ----
        int t = cb * 256 + threadIdx.x;   // 0..16383
        int k = t >> 7, j = t & 127;
        int jt = j >> 4, r = j & 15, kt = k >> 5, kg = (k >> 3) & 3, e = k & 7;
        int flin = (jt * 4 + kt) * 512 + (kg * 16 + r) * 8 + e;
        wtf1[flin] = f2h_bits(W1[t]);
        wtf2[flin] = f2h_bits(W2[t]);
        return;
    }
    // ---- x (f32) -> xh (fp16), 8 elems/thread ----
    int t = (cb - 64) * 256 + threadIdx.x;
    if (t >= n8) return;
    float4 x0 = reinterpret_cast<const float4*>(x)[(size_t)t * 2];
    float4 x1 = reinterpret_cast<const float4*>(x)[(size_t)t * 2 + 1];
    ushort8v o;
    o[0] = f2h_bits(x0.x); o[1] = f2h_bits(x0.y);
    o[2] = f2h_bits(x0.z); o[3] = f2h_bits(x0.w);
    o[4] = f2h_bits(x1.x); o[5] = f2h_bits(x1.y);
    o[6] = f2h_bits(x1.z); o[7] = f2h_bits(x1.w);
    reinterpret_cast<ushort8v*>(xh)[t] = o;
}

// ---- Fused: bucket gather -> LDS -> 2x f16 MFMA -> coalesced f32 y ----
__global__ __launch_bounds__(128, 4) void fused_kernel(
    const unsigned short* __restrict__ xh, const int* __restrict__ cnt,
    const unsigned int* __restrict__ esrt,
    const int4* __restrict__ ovf, const int* __restrict__ ovf_cnt,
    const unsigned short* __restrict__ wtf1,
    const unsigned short* __restrict__ wtf2,
    const float* __restrict__ b1, const float* __restrict__ b2,
    float* __restrict__ y, int N)
{
    __shared__ __align__(16) unsigned short Hs[32 * 128];
    int tid = threadIdx.x;
    int node0 = blockIdx.x * 32;
    int ovfc = *ovf_cnt;   // ~25 entries; uniform L2-hit load

    // Phase 1: gather. 8 groups x 16 lanes; group g owns rows {g, 8+g, 16+g, 24+g}.
    {
        int g = tid >> 4, l = tid & 15;
        const h8* xr = reinterpret_cast<const h8*>(xh);

        int degA[4];
        #pragma unroll
        for (int it = 0; it < 4; ++it) {
            int node = node0 + it * 8 + g;
            int nn = (node < N) ? node : N - 1;
            degA[it] = cnt[nn];
        }
        int sqA[4], wvA[4];          // per-lane decoded (src, packed-h2 weight)
        h8 selfA[4];
        #pragma unroll
        for (int it = 0; it < 4; ++it) {
            int node = node0 + it * 8 + g;
            int nn = (node < N) ? node : N - 1;
            unsigned int rec = 0;
            if (l < min(degA[it], CAP)) rec = esrt[(size_t)nn * CAP + l];
            sqA[it] = (int)(rec >> 15);
            _Float16 wh = (_Float16)((float)(rec & 32767u) * (1.f / 32767.f));
            union { h2 h; int i; } pw; pw.h = (h2){wh, wh};
            wvA[it] = pw.i;
            selfA[it] = xr[(size_t)nn * 16 + l];
        }

        #pragma unroll
        for (int it = 0; it < 4; ++it) {
            int m = it * 8 + g;
            int node = node0 + m;
            h8 acc = selfA[it];                    // self-term (EPS=0)
            int deg = min(degA[it], CAP);
            for (int j = 0; j < deg; j += 8) {
                h8 v[8]; int wb[8];
                #pragma unroll
                for (int q = 0; q < 8; ++q) {
                    int sq = __shfl(sqA[it], j + q, 16);
                    wb[q]  = __shfl(wvA[it], j + q, 16);
                    v[q] = xr[(size_t)sq * 16 + l];
                }
                #pragma unroll
                for (int q = 0; q < 8; ++q) {
                    union { int4 i; h8 h; } uw;
                    uw.i = make_int4(wb[q], wb[q], wb[q], wb[q]);
                    acc += uw.h * v[q];            // 4x v_pk_fma_f16 (pads w=0)
                }
            }
            // exact overflow path (deg > CAP): scan tiny COO list
            if (ovfc > 0 && degA[it] > CAP && node < N) {
                for (int o = 0; o < ovfc && o < OVF_MAX; ++o) {
                    int4 t4 = ovf[o];
                    if (t4.x == node) {
                        _Float16 wh = (_Float16)__int_as_float(t4.z);
                        union { h2 h; int i; } pw; pw.h = (h2){wh, wh};
                        union { int4 i; h8 h; } uw;
                        uw.i = make_int4(pw.i, pw.i, pw.i, pw.i);
                        acc += uw.h * xr[(size_t)t4.y * 16 + l];
                    }
                }
            }
            // lane l holds chunk l (8 elems); swizzled chunk slot l ^ (m&7)
            int soff = m * 128 + ((l ^ (m & 7)) << 3);
            *reinterpret_cast<h8*>(&Hs[soff]) = acc;
        }
    }
    __syncthreads();

    int wave = tid >> 6, lane = tid & 63;   // wave in {0,1}
    int r = lane & 15, kg = lane >> 4;
    int mr = wave * 16 + r;

    h8 a[4];
    #pragma unroll
    for (int kt = 0; kt < 4; ++kt)
        a[kt] = *reinterpret_cast<const h8*>(
            &Hs[mr * 128 + (((kt * 4 + kg) ^ (r & 7)) << 3)]);

    f32x4 acc1[8];
    #pragma unroll
    for (int jt = 0; jt < 8; ++jt) acc1[jt] = {0.f, 0.f, 0.f, 0.f};

    #pragma unroll
    for (int jt = 0; jt < 8; ++jt) {
        #pragma unroll
        for (int kt = 0; kt < 4; ++kt) {
            h8 b = *reinterpret_cast<const h8*>(
                wtf1 + ((jt * 4 + kt) << 9) + (lane << 3));   // coalesced
            acc1[jt] = __builtin_amdgcn_mfma_f32_16x16x32_f16(a[kt], b, acc1[jt], 0, 0, 0);
        }
    }

    #pragma unroll
    for (int jt = 0; jt < 8; ++jt) {
        float bias = b1[jt * 16 + r];
        int col = jt * 16 + r;
        #pragma unroll
        for (int reg = 0; reg < 4; ++reg) {
            int m2 = wave * 16 + kg * 4 + reg;
            float h = fmaxf(acc1[jt][reg] + bias, 0.0f);
            Hs[m2 * 128 + (((col >> 3) ^ (m2 & 7)) << 3) + (col & 7)] = f2h_bits(h);
        }
    }
    __syncthreads();

    h8 a2[4];
    #pragma unroll
    for (int kt = 0; kt < 4; ++kt)
        a2[kt] = *reinterpret_cast<const h8*>(
            &Hs[mr * 128 + (((kt * 4 + kg) ^ (r & 7)) << 3)]);

    f32x4 acc2[8];
    #pragma unroll
    for (int jt = 0; jt < 8; ++jt) acc2[jt] = {0.f, 0.f, 0.f, 0.f};

    #pragma unroll
    for (int jt = 0; jt < 8; ++jt) {
        #pragma unroll
        for (int kt = 0; kt < 4; ++kt) {
            h8 b = *reinterpret_cast<const h8*>(
                wtf2 + ((jt * 4 + kt) << 9) + (lane << 3));
            acc2[jt] = __builtin_amdgcn_mfma_f32_16x16x32_f16(a2[kt], b, acc2[jt], 0, 0, 0);
        }
    }

    // Coalesced y epilogue: stage each wave's 16x128 f32 tile in LDS (8 KB,
    // reusing Hs), then store float4/lane (full 64B lines -> no RFO fetch).
    float* Hf = reinterpret_cast<float*>(Hs);
    #pragma unroll
    for (int p = 0; p < 2; ++p) {
        __syncthreads();
        if (wave == p) {
            #pragma unroll
            for (int jt = 0; jt < 8; ++jt) {
                float bias = b2[jt * 16 + r];
                #pragma unroll
                for (int reg = 0; reg < 4; ++reg)
                    Hf[(kg * 4 + reg) * 128 + jt * 16 + r] = acc2[jt][reg] + bias;
            }
        }
        __syncthreads();
        #pragma unroll
        for (int q = 0; q < 4; ++q) {
            int f = q * 128 + tid;         // float4 index in [0,512)
            int row = f >> 5, c4 = f & 31;
            int orow = node0 + p * 16 + row;
            if (orow < N)
                reinterpret_cast<float4*>(y)[(size_t)orow * 32 + c4] =
                    reinterpret_cast<const float4*>(Hf)[f];
        }
    }
}

extern "C" void kernel_launch(void* const* d_in, const int* in_sizes, int n_in,
                              void* d_out, int out_size, void* d_ws, size_t ws_size,
                              hipStream_t stream) {
    const float* x  = (const float*)d_in[0];
    const int*   ei = (const int*)d_in[1];      // [2,E] as int32
    const float* ew = (const float*)d_in[2];
    const float* W1 = (const float*)d_in[3];
    const float* b1 = (const float*)d_in[4];
    const float* W2 = (const float*)d_in[5];
    const float* b2 = (const float*)d_in[6];
    float* y = (float*)d_out;

    int N = in_sizes[0] / 128;   // 100000
    int E = in_sizes[2];         // 600000
    const size_t ND = (size_t)N * 128;
    int n8 = (int)(ND / 8);
    int nxb = (n8 + 255) / 256;
    int nedge = (E + 255) / 256;
    int ntot = nedge + 64 + nxb;

    char* ws = (char*)d_ws;
    size_t off = 0;
    auto bump = [&](size_t bytes) {
        void* p = ws + off;
        off += (bytes + 255) & ~(size_t)255;
        return p;
    };
    // zero-region first (one memset covers cnt + ovf_cnt)
    size_t zstart = off;
    int*            cnt     = (int*)bump((size_t)N * 4);
    int*            ovf_cnt = (int*)bump(256);
    size_t zbytes = off - zstart;
    unsigned short* wtf1    = (unsigned short*)bump(128 * 128 * 2);
    unsigned short* wtf2    = (unsigned short*)bump(128 * 128 * 2);
    unsigned short* xh      = (unsigned short*)bump(ND * 2);           // 25.6 MB
    unsigned int*   esrt    = (unsigned int*)bump((size_t)N * CAP * 4); // 6.4 MB
    int4*           ovf     = (int4*)bump((size_t)OVF_MAX * 16);       // 128 KB

    const int* src = ei;
    const int* dst = ei + E;

    hipMemsetAsync(ws + zstart, 0, zbytes, stream);
    prep2_kernel<<<ntot, 256, 0, stream>>>(
        src, dst, ew, W1, W2, x, cnt, esrt, ovf, ovf_cnt,
        wtf1, wtf2, xh, E, n8, nedge, ntot);
    fused_kernel<<<(N + 31) / 32, 128, 0, stream>>>(
        xh, cnt, esrt, ovf, ovf_cnt, wtf1, wtf2, b1, b2, y, N);
}